// Round 6
// baseline (1653.582 us; speedup 1.0000x reference)
//
#include <hip/hip_runtime.h>
#include <cmath>

// All implicit ops single-rounded; FMA only where written explicitly
// (replicating XLA:CPU's FPOpFusion::Fast contraction choices).
#pragma clang fp contract(off)

#define PI_F     3.141592653589793f
#define TWOPI_F  6.283185307179586f
#define EPS_F    1e-5f
#define TWOEPS_F 2e-5f   // == f32(2e-5) exactly

// ---------------------------------------------------------------------------
// Bit-exact replica of glibc (>=2.28) scalar sinf/cosf (ARM optimized-routines,
// x86-64 baseline build: no FMA inside libm, double intermediates, one final
// rounding to f32). XLA:CPU lowers sine/cosine HLO to sinf/cosf libcalls.
// Valid for |y| < 120 (reduce_fast range) — rollout angles stay far below.
// ---------------------------------------------------------------------------
__device__ __forceinline__ double gl_poly_sin(double x, double x2) {
    const double ps1 = -0x1.555545995a603p-3;
    const double ps2 =  0x1.1107605230bc4p-7;
    const double ps3 = -0x1.994eb3774cf24p-13;
    double x3 = x * x2;
    double s1 = ps2 + x2 * ps3;
    double x7 = x3 * x2;
    double s  = x + x3 * ps1;
    return s + x7 * s1;
}

__device__ __forceinline__ double gl_poly_cos(double x2, double tbl) {
    const double pc0 =  0x1p+0;
    const double pc1 = -0x1.ffffffd0c621cp-2;
    const double pc2 =  0x1.55553e1068f19p-5;
    const double pc3 = -0x1.6c087e89a359dp-10;
    const double pc4 =  0x1.99343027bf8c3p-16;
    double C0 = tbl * pc0, C1 = tbl * pc1, C2 = tbl * pc2,
           C3 = tbl * pc3, C4 = tbl * pc4;
    double x4 = x2 * x2;
    double c2 = C3 + x2 * C4;
    double c1 = C0 + x2 * C1;
    double x6 = x4 * x2;
    double c  = c1 + x4 * C2;
    return c + x6 * c2;
}

__device__ __forceinline__ double gl_reduce(double x, int* np_) {
    const double hpi_inv = 0x1.45F306DC9C883p+23;  // 2/pi * 2^24
    const double hpi     = 0x1.921FB54442D18p+0;   // pi/2
    double r = x * hpi_inv;
    int n = ((int)r + 0x800000) >> 24;
    *np_ = n;
    return x - (double)n * hpi;                    // separate mul + sub
}

__device__ __forceinline__ double gl_signv(int n) {
    int k = n & 3;                                  // sign[4] = {1,-1,-1,1}
    return (k == 0 || k == 3) ? 1.0 : -1.0;
}

__device__ __forceinline__ float gl_sinf(float y) {
    unsigned abstop = (__float_as_uint(y) >> 20) & 0x7ff;
    double x = (double)y;
    if (abstop < 0x3f4) {                 // |y| below ~pi/4 band
        if (abstop < 0x398) return y;     // |y| < 2^-12: y is correctly rounded
        return (float)gl_poly_sin(x, x * x);
    }
    int n;
    double xr = gl_reduce(x, &n);
    double s = gl_signv(n);
    if ((n & 1) == 0) {
        return (float)gl_poly_sin(xr * s, xr * xr);
    } else {
        double tbl = (n & 2) ? -1.0 : 1.0;
        return (float)gl_poly_cos(xr * xr, tbl);
    }
}

__device__ __forceinline__ float gl_cosf(float y) {
    unsigned abstop = (__float_as_uint(y) >> 20) & 0x7ff;
    double x = (double)y;
    if (abstop < 0x3f4) {
        if (abstop < 0x398) return 1.0f;
        return (float)gl_poly_cos(x * x, 1.0);
    }
    int n;
    double xr = gl_reduce(x, &n);
    double s = gl_signv(n);
    int m = n ^ 1;                        // cosf uses parity n^1
    if ((m & 1) == 0) {
        return (float)gl_poly_sin(xr * s, xr * xr);
    } else {
        double tbl = (n & 2) ? -1.0 : 1.0;
        return (float)gl_poly_cos(xr * xr, tbl);
    }
}

// jnp.mod for positive divisor: trunc-rem (fmod, exact) then sign fixup.
__device__ __forceinline__ float angnorm(float x) {
    float t = x + PI_F;
    float r = fmodf(t, TWOPI_F);
    if (r < 0.0f) r += TWOPI_F;
    return r - PI_F;
}

// ---------------------------------------------------------------------------
// Hamiltonian with XLA:CPU FMA contraction (one-use fmul+fadd/fsub fused,
// N0-operand first):
//   denom = 2 * fma(s, s, 1)
//   num   = fma(-(2*p1)*p2, cos, fma(p1, p1, 2*(p2*p2)))
//   H     = fma(10, (1-c1)+(1-c2), num/denom)
// ---------------------------------------------------------------------------
__device__ __forceinline__ float ham_eval(float p1, float p2,
                                          float sdq, float cdq,
                                          float c1, float c2) {
    float denom = 2.0f * __builtin_fmaf(sdq, sdq, 1.0f);
    float B  = 2.0f * (p2 * p2);
    float AB = __builtin_fmaf(p1, p1, B);
    float t  = (2.0f * p1) * p2;
    float num = __builtin_fmaf(-t, cdq, AB);
    float T = num / denom;                       // IEEE f32 divide (vdivss)
    float VV = (1.0f - c1) + (1.0f - c2);
    return __builtin_fmaf(10.0f, VV, T);
}

struct Trig { float sdq, cdq, c1, c2; };

__device__ __forceinline__ void qtrig(float q1, float q2, Trig& t) {
    float dq = q1 - q2;
    t.sdq = gl_sinf(dq);
    t.cdq = gl_cosf(dq);
    t.c1  = gl_cosf(q1);
    t.c2  = gl_cosf(q2);
}

__device__ __forceinline__ void grads_full(float q1, float q2, float p1, float p2,
                                           const Trig& t,
                                           float& dHq1, float& dHq2,
                                           float& dHp1, float& dHp2) {
    {
        float q1p = q1 + EPS_F, q1m = q1 - EPS_F;
        float dqa = q1p - q2,   dqb = q1m - q2;
        float Hp = ham_eval(p1, p2, gl_sinf(dqa), gl_cosf(dqa), gl_cosf(q1p), t.c2);
        float Hm = ham_eval(p1, p2, gl_sinf(dqb), gl_cosf(dqb), gl_cosf(q1m), t.c2);
        dHq1 = (Hp - Hm) / TWOEPS_F;
    }
    {
        float q2p = q2 + EPS_F, q2m = q2 - EPS_F;
        float dqc = q1 - q2p,   dqd = q1 - q2m;
        float Hp = ham_eval(p1, p2, gl_sinf(dqc), gl_cosf(dqc), t.c1, gl_cosf(q2p));
        float Hm = ham_eval(p1, p2, gl_sinf(dqd), gl_cosf(dqd), t.c1, gl_cosf(q2m));
        dHq2 = (Hp - Hm) / TWOEPS_F;
    }
    {
        float Hp = ham_eval(p1 + EPS_F, p2, t.sdq, t.cdq, t.c1, t.c2);
        float Hm = ham_eval(p1 - EPS_F, p2, t.sdq, t.cdq, t.c1, t.c2);
        dHp1 = (Hp - Hm) / TWOEPS_F;
    }
    {
        float Hp = ham_eval(p1, p2 + EPS_F, t.sdq, t.cdq, t.c1, t.c2);
        float Hm = ham_eval(p1, p2 - EPS_F, t.sdq, t.cdq, t.c1, t.c2);
        dHp2 = (Hp - Hm) / TWOEPS_F;
    }
}

// p-only gradient (midpoint call: reference's dH_dq lanes are dead-code there).
__device__ __forceinline__ void grads_p(const Trig& t, float p1, float p2,
                                        float& dHp1, float& dHp2) {
    {
        float Hp = ham_eval(p1 + EPS_F, p2, t.sdq, t.cdq, t.c1, t.c2);
        float Hm = ham_eval(p1 - EPS_F, p2, t.sdq, t.cdq, t.c1, t.c2);
        dHp1 = (Hp - Hm) / TWOEPS_F;
    }
    {
        float Hp = ham_eval(p1, p2 + EPS_F, t.sdq, t.cdq, t.c1, t.c2);
        float Hm = ham_eval(p1, p2 - EPS_F, t.sdq, t.cdq, t.c1, t.c2);
        dHp2 = (Hp - Hm) / TWOEPS_F;
    }
}

__global__ __launch_bounds__(256)
void mpc_rollout_kernel(const float* __restrict__ q0,
                        const float* __restrict__ p0,
                        const float* __restrict__ actions,
                        const float* __restrict__ target,
                        float* __restrict__ out,
                        int n, int T) {
    int i = blockIdx.x * blockDim.x + threadIdx.x;
    if (i >= n) return;

    float q1 = q0[2 * i],  q2 = q0[2 * i + 1];
    float p1 = p0[2 * i],  p2 = p0[2 * i + 1];
    float tg1 = target[0], tg2 = target[1];
    const float* act = actions + (size_t)i * (size_t)T;

    // XLA reduce: strict sequential accumulation in time order
    float running = 0.0f;

#pragma unroll 1
    for (int ts = 0; ts < T; ++ts) {
        float a = act[ts];

        // running cost at the PRE-step state (trajectory index ts), contracted:
        // pos = fma(e1,e1, e2*e2); vel = fma(p1,p1, p2*p2);
        // c = fma(0.01, a*a, pos+vel)
        {
            float e1 = angnorm(q1 - tg1);
            float e2 = angnorm(q2 - tg2);
            float pos = __builtin_fmaf(e1, e1, e2 * e2);
            float vel = __builtin_fmaf(p1, p1, p2 * p2);
            float c = __builtin_fmaf(0.01f, a * a, pos + vel);
            running += c;
        }

        // --- symplectic step, XLA-contracted ---
        Trig t1; qtrig(q1, q2, t1);
        float dq1g, dq2g, dp1g, dp2g;
        grads_full(q1, q2, p1, p2, t1, dq1g, dq2g, dp1g, dp2g);

        // p_half = fma(-0.001, dH_dp, fma(-0.01, dH_dq, p))
        float ph1 = __builtin_fmaf(-0.001f, dp1g, __builtin_fmaf(-0.01f, dq1g, p1));
        float ph2 = __builtin_fmaf(-0.001f, dp2g, __builtin_fmaf(-0.01f, dq2g, p2));

        float dpm1, dpm2;
        grads_p(t1, ph1, ph2, dpm1, dpm2);   // q unchanged -> t1 reuse bit-exact

        // q_new = fma(0.02, dH_dp_mid, q)
        float qn1 = __builtin_fmaf(0.02f, dpm1, q1);
        float qn2 = __builtin_fmaf(0.02f, dpm2, q2);

        Trig t3; qtrig(qn1, qn2, t3);
        float dq1e, dq2e, dp1e, dp2e;
        grads_full(qn1, qn2, ph1, ph2, t3, dq1e, dq2e, dp1e, dp2e);

        float pn1 = __builtin_fmaf(-0.001f, dp1e, __builtin_fmaf(-0.01f, dq1e, ph1));
        float pn2 = __builtin_fmaf(-0.001f, dp2e, __builtin_fmaf(-0.01f, dq2e, ph2));
        // torque: p[1] + a*DT -> fma(a, 0.02, p[1])
        pn2 = __builtin_fmaf(a, 0.02f, pn2);

        q1 = qn1; q2 = qn2; p1 = pn1; p2 = pn2;
    }

    // terminal cost at trajectory index T, contracted reduce:
    // S = fma(e2,e2, e1*e1); S2 = fma(p2,p2, p1*p1); term = fma(10, S, S2)
    float e1 = angnorm(q1 - tg1);
    float e2 = angnorm(q2 - tg2);
    float S  = __builtin_fmaf(e2, e2, e1 * e1);
    float S2 = __builtin_fmaf(p2, p2, p1 * p1);
    float term = __builtin_fmaf(10.0f, S, S2);

    out[i] = running + term;
}

extern "C" void kernel_launch(void* const* d_in, const int* in_sizes, int n_in,
                              void* d_out, int out_size, void* d_ws, size_t ws_size,
                              hipStream_t stream) {
    const float* q0      = (const float*)d_in[0];
    const float* p0      = (const float*)d_in[1];
    const float* actions = (const float*)d_in[2];
    const float* target  = (const float*)d_in[3];
    float* out = (float*)d_out;

    int n = in_sizes[0] / 2;        // q0 is (n, 2)
    int T = in_sizes[2] / n;        // actions is (n, T)

    int block = 256;
    int grid = (n + block - 1) / block;
    mpc_rollout_kernel<<<grid, block, 0, stream>>>(q0, p0, actions, target, out, n, T);
}

// Round 7
// 1036.876 us; speedup vs baseline: 1.5948x; 1.5948x over previous
//
#include <hip/hip_runtime.h>
#include <cmath>

// All implicit ops single-rounded; FMA only where written explicitly
// (replicating XLA:CPU's FPOpFusion::Fast contraction). Output must stay
// BIT-IDENTICAL to round 6 (passed, absmax 16.0).
#pragma clang fp contract(off)

#define PI_F     3.141592653589793f
#define TWOPI_F  6.283185307179586f
#define EPS_F    1e-5f
#define TWOEPS_F 2e-5f   // == f32(2e-5) exactly

// ---------------------------------------------------------------------------
// Branchless fused replica of glibc (>=2.28) scalar sinf/cosf.
// Bit-exactness argument vs the branchy original (round 6, passed):
//  * small path (|y|<0.75): reduce gives n=0, xr = y - 0.0*hpi = y exactly,
//    so the general path computes the identical poly on identical bits.
//  * tiny path (|y|<2^-12): general path's (float)poly rounds to y (sin) and
//    1.0f (cos) — correction < 0.4 ulp, never crosses a rounding boundary.
//    (Only sin(-0.0) returns +0.0 instead of -0.0; sin enters H only squared.)
//  * sin poly is exactly odd (IEEE sign symmetry), so poly(xr*s) == s*poly(xr);
//    table[1]'s negated cos coeffs give exactly -poly_cos(table[0]) — signs
//    are applied as exact negations after one poly evaluation each.
//  * sign/parity selects reproduce glibc's n&1 / n&2 / table logic exactly.
// Valid for |y| < 120 (reduce_fast range); rollout angles stay |q| < ~30.
// ---------------------------------------------------------------------------
__device__ __forceinline__ void gl_sincos(float y, float& sout, float& cout) {
    const double hpi_inv = 0x1.45F306DC9C883p+23;  // 2/pi * 2^24
    const double hpi     = 0x1.921FB54442D18p+0;   // pi/2
    const double ps1 = -0x1.555545995a603p-3;
    const double ps2 =  0x1.1107605230bc4p-7;
    const double ps3 = -0x1.994eb3774cf24p-13;
    const double pc1 = -0x1.ffffffd0c621cp-2;
    const double pc2 =  0x1.55553e1068f19p-5;
    const double pc3 = -0x1.6c087e89a359dp-10;
    const double pc4 =  0x1.99343027bf8c3p-16;

    double x = (double)y;
    double r = x * hpi_inv;
    int n = ((int)r + 0x800000) >> 24;     // trunc + biased round, glibc exact
    double xr = x - (double)n * hpi;       // separate mul + sub (no fma)
    double x2 = xr * xr;

    // sine poly at xr, glibc grouping (sign applied afterwards, exact)
    double x3 = xr * x2;
    double s1 = ps2 + x2 * ps3;
    double x7 = x3 * x2;
    double ss = xr + x3 * ps1;
    double psin = ss + x7 * s1;

    // cosine poly at x2, positive table, glibc grouping
    double x4 = x2 * x2;
    double c2 = pc3 + x2 * pc4;
    double c1 = 1.0 + x2 * pc1;
    double x6 = x4 * x2;
    double cc = c1 + x4 * pc2;
    double pcos = cc + x6 * c2;

    // glibc parity/sign logic (verified n = -1..3 against s_sinf.c/s_cosf.c)
    double s_sel = (n & 1) ? pcos : psin;
    double c_sel = (n & 1) ? psin : pcos;
    double s = (n & 2) ? -s_sel : s_sel;
    double c = ((n + 1) & 2) ? -c_sel : c_sel;
    sout = (float)s;
    cout = (float)c;
}

__device__ __forceinline__ float gl_cosf(float y) {
    float s, c;
    gl_sincos(y, s, c);
    return c;
}

// jnp.mod for positive divisor: trunc-rem (fmod, exact) then sign fixup.
__device__ __forceinline__ float angnorm(float x) {
    float t = x + PI_F;
    float r = fmodf(t, TWOPI_F);
    if (r < 0.0f) r += TWOPI_F;
    return r - PI_F;
}

// Hamiltonian with XLA:CPU FMA contraction (unchanged from round 6 — passed):
//   denom = 2 * fma(s, s, 1)
//   num   = fma(-(2*p1)*p2, cos, fma(p1, p1, 2*(p2*p2)))
//   H     = fma(10, (1-c1)+(1-c2), num/denom)
__device__ __forceinline__ float ham_eval(float p1, float p2,
                                          float sdq, float cdq,
                                          float c1, float c2) {
    float denom = 2.0f * __builtin_fmaf(sdq, sdq, 1.0f);
    float B  = 2.0f * (p2 * p2);
    float AB = __builtin_fmaf(p1, p1, B);
    float t  = (2.0f * p1) * p2;
    float num = __builtin_fmaf(-t, cdq, AB);
    float T = num / denom;                       // IEEE f32 divide
    float VV = (1.0f - c1) + (1.0f - c2);
    return __builtin_fmaf(10.0f, VV, T);
}

struct Trig { float sdq, cdq, c1, c2; };

__device__ __forceinline__ void qtrig(float q1, float q2, Trig& t) {
    float dq = q1 - q2;
    gl_sincos(dq, t.sdq, t.cdq);
    t.c1 = gl_cosf(q1);
    t.c2 = gl_cosf(q2);
}

__device__ __forceinline__ void grads_full(float q1, float q2, float p1, float p2,
                                           const Trig& t,
                                           float& dHq1, float& dHq2,
                                           float& dHp1, float& dHp2) {
    {
        float q1p = q1 + EPS_F, q1m = q1 - EPS_F;
        float sa, ca, sb, cb;
        gl_sincos(q1p - q2, sa, ca);
        gl_sincos(q1m - q2, sb, cb);
        float Hp = ham_eval(p1, p2, sa, ca, gl_cosf(q1p), t.c2);
        float Hm = ham_eval(p1, p2, sb, cb, gl_cosf(q1m), t.c2);
        dHq1 = (Hp - Hm) / TWOEPS_F;
    }
    {
        float q2p = q2 + EPS_F, q2m = q2 - EPS_F;
        float sc, cc, sd, cd;
        gl_sincos(q1 - q2p, sc, cc);
        gl_sincos(q1 - q2m, sd, cd);
        float Hp = ham_eval(p1, p2, sc, cc, t.c1, gl_cosf(q2p));
        float Hm = ham_eval(p1, p2, sd, cd, t.c1, gl_cosf(q2m));
        dHq2 = (Hp - Hm) / TWOEPS_F;
    }
    {
        float Hp = ham_eval(p1 + EPS_F, p2, t.sdq, t.cdq, t.c1, t.c2);
        float Hm = ham_eval(p1 - EPS_F, p2, t.sdq, t.cdq, t.c1, t.c2);
        dHp1 = (Hp - Hm) / TWOEPS_F;
    }
    {
        float Hp = ham_eval(p1, p2 + EPS_F, t.sdq, t.cdq, t.c1, t.c2);
        float Hm = ham_eval(p1, p2 - EPS_F, t.sdq, t.cdq, t.c1, t.c2);
        dHp2 = (Hp - Hm) / TWOEPS_F;
    }
}

// p-only gradient (midpoint call: reference's dH_dq lanes are dead code there).
__device__ __forceinline__ void grads_p(const Trig& t, float p1, float p2,
                                        float& dHp1, float& dHp2) {
    {
        float Hp = ham_eval(p1 + EPS_F, p2, t.sdq, t.cdq, t.c1, t.c2);
        float Hm = ham_eval(p1 - EPS_F, p2, t.sdq, t.cdq, t.c1, t.c2);
        dHp1 = (Hp - Hm) / TWOEPS_F;
    }
    {
        float Hp = ham_eval(p1, p2 + EPS_F, t.sdq, t.cdq, t.c1, t.c2);
        float Hm = ham_eval(p1, p2 - EPS_F, t.sdq, t.cdq, t.c1, t.c2);
        dHp2 = (Hp - Hm) / TWOEPS_F;
    }
}

__global__ __launch_bounds__(256)
void mpc_rollout_kernel(const float* __restrict__ q0,
                        const float* __restrict__ p0,
                        const float* __restrict__ actions,
                        const float* __restrict__ target,
                        float* __restrict__ out,
                        int n, int T) {
    int i = blockIdx.x * blockDim.x + threadIdx.x;
    if (i >= n) return;

    float q1 = q0[2 * i],  q2 = q0[2 * i + 1];
    float p1 = p0[2 * i],  p2 = p0[2 * i + 1];
    float tg1 = target[0], tg2 = target[1];
    const float* act = actions + (size_t)i * (size_t)T;

    // XLA reduce: strict sequential accumulation in time order
    float running = 0.0f;

#pragma unroll 1
    for (int ts = 0; ts < T; ++ts) {
        float a = act[ts];

        // running cost at the PRE-step state (trajectory index ts), contracted
        {
            float e1 = angnorm(q1 - tg1);
            float e2 = angnorm(q2 - tg2);
            float pos = __builtin_fmaf(e1, e1, e2 * e2);
            float vel = __builtin_fmaf(p1, p1, p2 * p2);
            float c = __builtin_fmaf(0.01f, a * a, pos + vel);
            running += c;
        }

        // --- symplectic step, XLA-contracted (identical to round 6) ---
        Trig t1; qtrig(q1, q2, t1);
        float dq1g, dq2g, dp1g, dp2g;
        grads_full(q1, q2, p1, p2, t1, dq1g, dq2g, dp1g, dp2g);

        float ph1 = __builtin_fmaf(-0.001f, dp1g, __builtin_fmaf(-0.01f, dq1g, p1));
        float ph2 = __builtin_fmaf(-0.001f, dp2g, __builtin_fmaf(-0.01f, dq2g, p2));

        float dpm1, dpm2;
        grads_p(t1, ph1, ph2, dpm1, dpm2);   // q unchanged -> t1 reuse bit-exact

        float qn1 = __builtin_fmaf(0.02f, dpm1, q1);
        float qn2 = __builtin_fmaf(0.02f, dpm2, q2);

        Trig t3; qtrig(qn1, qn2, t3);
        float dq1e, dq2e, dp1e, dp2e;
        grads_full(qn1, qn2, ph1, ph2, t3, dq1e, dq2e, dp1e, dp2e);

        float pn1 = __builtin_fmaf(-0.001f, dp1e, __builtin_fmaf(-0.01f, dq1e, ph1));
        float pn2 = __builtin_fmaf(-0.001f, dp2e, __builtin_fmaf(-0.01f, dq2e, ph2));
        pn2 = __builtin_fmaf(a, 0.02f, pn2);   // torque on p[1]

        q1 = qn1; q2 = qn2; p1 = pn1; p2 = pn2;
    }

    // terminal cost at trajectory index T, contracted
    float e1 = angnorm(q1 - tg1);
    float e2 = angnorm(q2 - tg2);
    float S  = __builtin_fmaf(e2, e2, e1 * e1);
    float S2 = __builtin_fmaf(p2, p2, p1 * p1);
    float term = __builtin_fmaf(10.0f, S, S2);

    out[i] = running + term;
}

extern "C" void kernel_launch(void* const* d_in, const int* in_sizes, int n_in,
                              void* d_out, int out_size, void* d_ws, size_t ws_size,
                              hipStream_t stream) {
    const float* q0      = (const float*)d_in[0];
    const float* p0      = (const float*)d_in[1];
    const float* actions = (const float*)d_in[2];
    const float* target  = (const float*)d_in[3];
    float* out = (float*)d_out;

    int n = in_sizes[0] / 2;        // q0 is (n, 2)
    int T = in_sizes[2] / n;        // actions is (n, T)

    int block = 256;
    int grid = (n + block - 1) / block;
    mpc_rollout_kernel<<<grid, block, 0, stream>>>(q0, p0, actions, target, out, n, T);
}

// Round 8
// 715.919 us; speedup vs baseline: 2.3097x; 1.4483x over previous
//
#include <hip/hip_runtime.h>
#include <cmath>

// All implicit ops single-rounded; FMA only where written explicitly
// (replicating XLA:CPU's FPOpFusion::Fast contraction). Output must stay
// BIT-IDENTICAL to rounds 6/7 (passed, absmax 16.0).
#pragma clang fp contract(off)

#define PI_F     3.141592653589793f
#define TWOPI_F  6.283185307179586f
#define EPS_F    1e-5f
#define TWOEPS_F 2e-5f   // == f32(2e-5) exactly

// ---------------------------------------------------------------------------
// Branchless fused replica of glibc (>=2.28) scalar sinf/cosf (see round 6/7
// notes for the bit-exactness argument). One refinement vs round 7: the
// parity/sign selects are applied AFTER the f64->f32 rounding — IEEE rounding
// commutes with sign flip, so results are bit-identical while the cndmasks
// shrink from 64-bit to 32-bit.
// Valid for |y| < 120 (reduce_fast range); rollout angles stay |q| < ~30.
// ---------------------------------------------------------------------------
__device__ __forceinline__ void gl_sincos(float y, float& sout, float& cout) {
    const double hpi_inv = 0x1.45F306DC9C883p+23;  // 2/pi * 2^24
    const double hpi     = 0x1.921FB54442D18p+0;   // pi/2
    const double ps1 = -0x1.555545995a603p-3;
    const double ps2 =  0x1.1107605230bc4p-7;
    const double ps3 = -0x1.994eb3774cf24p-13;
    const double pc1 = -0x1.ffffffd0c621cp-2;
    const double pc2 =  0x1.55553e1068f19p-5;
    const double pc3 = -0x1.6c087e89a359dp-10;
    const double pc4 =  0x1.99343027bf8c3p-16;

    double x = (double)y;
    double r = x * hpi_inv;
    int n = ((int)r + 0x800000) >> 24;     // trunc + biased round, glibc exact
    double xr = x - (double)n * hpi;       // separate mul + sub (no fma)
    double x2 = xr * xr;

    // sine poly at xr, glibc grouping
    double x3 = xr * x2;
    double s1 = ps2 + x2 * ps3;
    double x7 = x3 * x2;
    double ss = xr + x3 * ps1;
    double psin = ss + x7 * s1;

    // cosine poly at x2, positive table, glibc grouping
    double x4 = x2 * x2;
    double c2 = pc3 + x2 * pc4;
    double c1 = 1.0 + x2 * pc1;
    double x6 = x4 * x2;
    double cc = c1 + x4 * pc2;
    double pcos = cc + x6 * c2;

    // round once, then exact sign/parity selects in f32
    float psin_f = (float)psin;
    float pcos_f = (float)pcos;
    float s_sel = (n & 1) ? pcos_f : psin_f;
    float c_sel = (n & 1) ? psin_f : pcos_f;
    sout = (n & 2) ? -s_sel : s_sel;
    cout = ((n + 1) & 2) ? -c_sel : c_sel;
}

__device__ __forceinline__ float gl_cosf(float y) {
    float s, c;
    gl_sincos(y, s, c);
    return c;
}

// jnp.mod for positive divisor: trunc-rem (fmod, exact) then sign fixup.
__device__ __forceinline__ float angnorm(float x) {
    float t = x + PI_F;
    float r = fmodf(t, TWOPI_F);
    if (r < 0.0f) r += TWOPI_F;
    return r - PI_F;
}

// Hamiltonian with XLA:CPU FMA contraction (unchanged from rounds 6/7):
//   denom = 2 * fma(s, s, 1)
//   num   = fma(-(2*p1)*p2, cos, fma(p1, p1, 2*(p2*p2)))
//   H     = fma(10, (1-c1)+(1-c2), num/denom)
__device__ __forceinline__ float ham_eval(float p1, float p2,
                                          float sdq, float cdq,
                                          float c1, float c2) {
    float denom = 2.0f * __builtin_fmaf(sdq, sdq, 1.0f);
    float B  = 2.0f * (p2 * p2);
    float AB = __builtin_fmaf(p1, p1, B);
    float t  = (2.0f * p1) * p2;
    float num = __builtin_fmaf(-t, cdq, AB);
    float T = num / denom;                       // IEEE f32 divide
    float VV = (1.0f - c1) + (1.0f - c2);
    return __builtin_fmaf(10.0f, VV, T);
}

// ---------------------------------------------------------------------------
// Cross-step trig cache. ALL trig is a pure function of (q1,q2); q doesn't
// change between the end-of-step grads call at q_new and the next step's
// start-of-step grads + qtrig at the same q — so the 11 unique evaluations
// (3 unperturbed + 8 perturbed) are computed once per q and carried.
// Identical bits, half the trig calls (22 -> 11 per step).
// ---------------------------------------------------------------------------
struct QTrig {
    float sdq, cdq, c1, c2;     // sincos(q1-q2), cos(q1), cos(q2)
    float sa, ca, c1p;          // sincos((q1+e)-q2), cos(q1+e)
    float sb, cb, c1m;          // sincos((q1-e)-q2), cos(q1-e)
    float sc, cc, c2p;          // sincos(q1-(q2+e)), cos(q2+e)
    float sd, cd, c2m;          // sincos(q1-(q2-e)), cos(q2-e)
};

__device__ __forceinline__ void qtrig_all(float q1, float q2, QTrig& t) {
    gl_sincos(q1 - q2, t.sdq, t.cdq);
    t.c1 = gl_cosf(q1);
    t.c2 = gl_cosf(q2);
    float q1p = q1 + EPS_F, q1m = q1 - EPS_F;
    gl_sincos(q1p - q2, t.sa, t.ca);  t.c1p = gl_cosf(q1p);
    gl_sincos(q1m - q2, t.sb, t.cb);  t.c1m = gl_cosf(q1m);
    float q2p = q2 + EPS_F, q2m = q2 - EPS_F;
    gl_sincos(q1 - q2p, t.sc, t.cc);  t.c2p = gl_cosf(q2p);
    gl_sincos(q1 - q2m, t.sd, t.cd);  t.c2m = gl_cosf(q2m);
}

// Full 4-dim FD gradient from cached trig (identical arithmetic to round 7).
__device__ __forceinline__ void grads_full(const QTrig& t, float p1, float p2,
                                           float& dHq1, float& dHq2,
                                           float& dHp1, float& dHp2) {
    {
        float Hp = ham_eval(p1, p2, t.sa, t.ca, t.c1p, t.c2);
        float Hm = ham_eval(p1, p2, t.sb, t.cb, t.c1m, t.c2);
        dHq1 = (Hp - Hm) / TWOEPS_F;
    }
    {
        float Hp = ham_eval(p1, p2, t.sc, t.cc, t.c1, t.c2p);
        float Hm = ham_eval(p1, p2, t.sd, t.cd, t.c1, t.c2m);
        dHq2 = (Hp - Hm) / TWOEPS_F;
    }
    {
        float Hp = ham_eval(p1 + EPS_F, p2, t.sdq, t.cdq, t.c1, t.c2);
        float Hm = ham_eval(p1 - EPS_F, p2, t.sdq, t.cdq, t.c1, t.c2);
        dHp1 = (Hp - Hm) / TWOEPS_F;
    }
    {
        float Hp = ham_eval(p1, p2 + EPS_F, t.sdq, t.cdq, t.c1, t.c2);
        float Hm = ham_eval(p1, p2 - EPS_F, t.sdq, t.cdq, t.c1, t.c2);
        dHp2 = (Hp - Hm) / TWOEPS_F;
    }
}

// p-only gradient (midpoint call: reference's dH_dq lanes are dead code there).
__device__ __forceinline__ void grads_p(const QTrig& t, float p1, float p2,
                                        float& dHp1, float& dHp2) {
    {
        float Hp = ham_eval(p1 + EPS_F, p2, t.sdq, t.cdq, t.c1, t.c2);
        float Hm = ham_eval(p1 - EPS_F, p2, t.sdq, t.cdq, t.c1, t.c2);
        dHp1 = (Hp - Hm) / TWOEPS_F;
    }
    {
        float Hp = ham_eval(p1, p2 + EPS_F, t.sdq, t.cdq, t.c1, t.c2);
        float Hm = ham_eval(p1, p2 - EPS_F, t.sdq, t.cdq, t.c1, t.c2);
        dHp2 = (Hp - Hm) / TWOEPS_F;
    }
}

__global__ __launch_bounds__(256)
void mpc_rollout_kernel(const float* __restrict__ q0,
                        const float* __restrict__ p0,
                        const float* __restrict__ actions,
                        const float* __restrict__ target,
                        float* __restrict__ out,
                        int n, int T) {
    int i = blockIdx.x * blockDim.x + threadIdx.x;
    if (i >= n) return;

    float q1 = q0[2 * i],  q2 = q0[2 * i + 1];
    float p1 = p0[2 * i],  p2 = p0[2 * i + 1];
    float tg1 = target[0], tg2 = target[1];
    const float* act = actions + (size_t)i * (size_t)T;

    // XLA reduce: strict sequential accumulation in time order
    float running = 0.0f;

    QTrig qt;
    qtrig_all(q1, q2, qt);          // trig for the initial q

#pragma unroll 1
    for (int ts = 0; ts < T; ++ts) {
        float a = act[ts];

        // running cost at the PRE-step state (trajectory index ts), contracted
        {
            float e1 = angnorm(q1 - tg1);
            float e2 = angnorm(q2 - tg2);
            float pos = __builtin_fmaf(e1, e1, e2 * e2);
            float vel = __builtin_fmaf(p1, p1, p2 * p2);
            float c = __builtin_fmaf(0.01f, a * a, pos + vel);
            running += c;
        }

        // --- symplectic step, XLA-contracted (identical bits to round 7) ---
        float dq1g, dq2g, dp1g, dp2g;
        grads_full(qt, p1, p2, dq1g, dq2g, dp1g, dp2g);   // trig cached

        float ph1 = __builtin_fmaf(-0.001f, dp1g, __builtin_fmaf(-0.01f, dq1g, p1));
        float ph2 = __builtin_fmaf(-0.001f, dp2g, __builtin_fmaf(-0.01f, dq2g, p2));

        float dpm1, dpm2;
        grads_p(qt, ph1, ph2, dpm1, dpm2);   // q unchanged -> same cached trig

        float qn1 = __builtin_fmaf(0.02f, dpm1, q1);
        float qn2 = __builtin_fmaf(0.02f, dpm2, q2);

        qtrig_all(qn1, qn2, qt);             // the ONLY trig work this step
        float dq1e, dq2e, dp1e, dp2e;
        grads_full(qt, ph1, ph2, dq1e, dq2e, dp1e, dp2e);

        float pn1 = __builtin_fmaf(-0.001f, dp1e, __builtin_fmaf(-0.01f, dq1e, ph1));
        float pn2 = __builtin_fmaf(-0.001f, dp2e, __builtin_fmaf(-0.01f, dq2e, ph2));
        pn2 = __builtin_fmaf(a, 0.02f, pn2);   // torque on p[1]

        q1 = qn1; q2 = qn2; p1 = pn1; p2 = pn2;
        // qt now holds trig for the new q -> reused at the next iteration
    }

    // terminal cost at trajectory index T, contracted
    float e1 = angnorm(q1 - tg1);
    float e2 = angnorm(q2 - tg2);
    float S  = __builtin_fmaf(e2, e2, e1 * e1);
    float S2 = __builtin_fmaf(p2, p2, p1 * p1);
    float term = __builtin_fmaf(10.0f, S, S2);

    out[i] = running + term;
}

extern "C" void kernel_launch(void* const* d_in, const int* in_sizes, int n_in,
                              void* d_out, int out_size, void* d_ws, size_t ws_size,
                              hipStream_t stream) {
    const float* q0      = (const float*)d_in[0];
    const float* p0      = (const float*)d_in[1];
    const float* actions = (const float*)d_in[2];
    const float* target  = (const float*)d_in[3];
    float* out = (float*)d_out;

    int n = in_sizes[0] / 2;        // q0 is (n, 2)
    int T = in_sizes[2] / n;        // actions is (n, T)

    int block = 256;
    int grid = (n + block - 1) / block;
    mpc_rollout_kernel<<<grid, block, 0, stream>>>(q0, p0, actions, target, out, n, T);
}